// Round 1
// baseline (1351.491 us; speedup 1.0000x reference)
//
#include <hip/hip_runtime.h>
#include <math.h>

#define S_ 4
#define R_ 2048
#define K_ 128
#define C_ 32
#define RES_ 128
#define G_ 128
#define H_ 128

// ws layout (in floats)
#define CODET_OFF 0
#define CODET_SZ  (S_*3*C_*RES_*RES_)   // 6291456
#define SR_OFF    (CODET_OFF + CODET_SZ)
#define SR_SZ     (S_*R_*K_*4)          // 4194304 (float4 per point)
#define W3T_OFF   (SR_OFF + SR_SZ)

// ---------------------------------------------------------------------------
// K0: transpose code (S,3,C,RES,RES) -> codeT (S,3,RES,RES,C)
// ---------------------------------------------------------------------------
__global__ __launch_bounds__(256) void k_transpose_code(
    const float* __restrict__ src, float* __restrict__ dst) {
  __shared__ float tile[32 * 65];
  const int t = threadIdx.x;
  const int slab = blockIdx.x >> 8;            // 12 slabs (s*3+pl)
  const int xy0 = (blockIdx.x & 255) << 6;     // 256 tiles of 64 texels
  const float* sp = src + slab * (C_ * RES_ * RES_);
  float* dp = dst + slab * (C_ * RES_ * RES_);
  const int i = t & 63, cg = t >> 6;
#pragma unroll
  for (int j = 0; j < 8; ++j) {
    int c = cg * 8 + j;
    tile[c * 65 + i] = sp[c * (RES_ * RES_) + xy0 + i];
  }
  __syncthreads();
  const int c2 = t & 31, xh = t >> 5;
#pragma unroll
  for (int j = 0; j < 8; ++j) {
    int xy = xh * 8 + j;
    dp[(xy0 + xy) * C_ + c2] = tile[c2 * 65 + xy];
  }
}

// ---------------------------------------------------------------------------
// K0b: W3 (128,4) -> W3T (4,128)
// ---------------------------------------------------------------------------
__global__ void k_prep_w3t(const float* __restrict__ W3, float* __restrict__ W3T) {
  const int t = threadIdx.x;  // 128 threads
  float4 r = *(const float4*)(W3 + t * 4);
  W3T[0 * H_ + t] = r.x;
  W3T[1 * H_ + t] = r.y;
  W3T[2 * H_ + t] = r.z;
  W3T[3 * H_ + t] = r.w;
}

// ---------------------------------------------------------------------------
// near/far helper (matches reference exactly in structure)
// ---------------------------------------------------------------------------
__device__ __forceinline__ void near_far(float ox, float oy, float oz,
                                         float dx, float dy, float dz,
                                         float& nearv, float& farv) {
  float ddx = fabsf(dx) < 1e-9f ? 1e-9f : dx;
  float ddy = fabsf(dy) < 1e-9f ? 1e-9f : dy;
  float ddz = fabsf(dz) < 1e-9f ? 1e-9f : dz;
  float ix = 1.f / ddx, iy = 1.f / ddy, iz = 1.f / ddz;
  float t1x = (-1.f - ox) * ix, t2x = (1.f - ox) * ix;
  float t1y = (-1.f - oy) * iy, t2y = (1.f - oy) * iy;
  float t1z = (-1.f - oz) * iz, t2z = (1.f - oz) * iz;
  float mnx = fminf(t1x, t2x), mxx = fmaxf(t1x, t2x);
  float mny = fminf(t1y, t2y), mxy = fmaxf(t1y, t2y);
  float mnz = fminf(t1z, t2z), mxz = fmaxf(t1z, t2z);
  nearv = fmaxf(fmaxf(fmaxf(mnx, mny), mnz), 0.2f);
  farv = fmaxf(fminf(fminf(mxx, mxy), mxz), nearv);
}

// ---------------------------------------------------------------------------
// K1: fused sampling + MLP. Block = 256 threads, 64 points (half a ray).
//   bufA: featsT[96][64] (k-major, XOR-swizzled 16B units) then h2[64][128]
//   bufB: h1T[128][64]  (k-major, XOR-swizzled)
// Thread GEMM tile: 4 points (m) x 8 channels (n).
// ---------------------------------------------------------------------------
__global__ __launch_bounds__(256) void k_fused(
    const float* __restrict__ rays_o, const float* __restrict__ rays_d,
    const float* __restrict__ codeT, const int* __restrict__ dgrid,
    const float* __restrict__ W1, const float* __restrict__ b1,
    const float* __restrict__ W2, const float* __restrict__ b2,
    const float* __restrict__ W3T, const float* __restrict__ b3,
    float* __restrict__ sr) {
  __shared__ __align__(16) float bufA[8192];
  __shared__ __align__(16) float bufB[8192];

  const int t = threadIdx.x;
  const int tn = t & 15, tm = t >> 4;   // GEMM role: n0 = 8*tn, m0 = 4*tm
  const int p = t >> 2, q = t & 3;      // sampling/output role: point p, part q
  const int pG = blockIdx.x * 64 + p;   // global point id
  const int s = pG >> 18;               // R_*K_ = 2^18
  const int r = (pG >> 7) & (R_ - 1);
  const int k = pG & (K_ - 1);

  const float* ob = rays_o + (s * R_ + r) * 3;
  const float* db = rays_d + (s * R_ + r) * 3;
  const float ox = ob[0], oy = ob[1], oz = ob[2];
  const float dx = db[0], dy = db[1], dz = db[2];
  float nearv, farv;
  near_far(ox, oy, oz, dx, dy, dz, nearv, farv);

  const float zs = nearv + (farv - nearv) * ((k + 0.5f) * (1.0f / K_));
  const float px = fminf(fmaxf(ox + dx * zs, -1.f), 1.f);
  const float py = fminf(fmaxf(oy + dy * zs, -1.f), 1.f);
  const float pz = fminf(fmaxf(oz + dz * zs, -1.f), 1.f);

  // occupancy (only the q==0 thread's value is consumed, in layer 3)
  const int i0 = min((int)((px + 1.f) * 64.f), G_ - 1);
  const int i1 = min((int)((py + 1.f) * 64.f), G_ - 1);
  const int i2 = min((int)((pz + 1.f) * 64.f), G_ - 1);
  const int occ = dgrid[((s * G_ + i0) * G_ + i1) * G_ + i2] > 0;

  // ---- triplane sampling: thread covers feats [24q, 24q+24) of its point ----
#pragma unroll
  for (int pl = 0; pl < 3; ++pl) {
    const float u = (pl == 2) ? py : px;
    const float v = (pl == 0) ? py : pz;
    const float fx = (u + 1.f) * 0.5f * 127.f;
    const float fy = (v + 1.f) * 0.5f * 127.f;
    const int xi = min((int)fx, RES_ - 2);
    const int yi = min((int)fy, RES_ - 2);
    const float wx = fx - (float)xi, wy = fy - (float)yi;
    const float w00 = (1.f - wx) * (1.f - wy);
    const float w01 = wx * (1.f - wy);
    const float w10 = (1.f - wx) * wy;
    const float w11 = wx * wy;
    const float* bp = codeT + ((s * 3 + pl) * (RES_ * RES_) + yi * RES_ + xi) * C_;
    const int c0 = max(24 * q - 32 * pl, 0);
    const int c1 = min(24 * q + 24 - 32 * pl, 32);
    const int pu = p >> 2, plo = p & 3;
    for (int c = c0; c < c1; c += 4) {
      const float4 A = *(const float4*)(bp + c);
      const float4 B = *(const float4*)(bp + C_ + c);
      const float4 Cv = *(const float4*)(bp + RES_ * C_ + c);
      const float4 D = *(const float4*)(bp + RES_ * C_ + C_ + c);
      const float f0 = w00 * A.x + w01 * B.x + w10 * Cv.x + w11 * D.x;
      const float f1 = w00 * A.y + w01 * B.y + w10 * Cv.y + w11 * D.y;
      const float f2 = w00 * A.z + w01 * B.z + w10 * Cv.z + w11 * D.z;
      const float f3 = w00 * A.w + w01 * B.w + w10 * Cv.w + w11 * D.w;
      const int f = pl * 32 + c;
      bufA[(f + 0) * 64 + ((pu ^ ((f + 0) & 7)) << 2) + plo] = f0;
      bufA[(f + 1) * 64 + ((pu ^ ((f + 1) & 7)) << 2) + plo] = f1;
      bufA[(f + 2) * 64 + ((pu ^ ((f + 2) & 7)) << 2) + plo] = f2;
      bufA[(f + 3) * 64 + ((pu ^ ((f + 3) & 7)) << 2) + plo] = f3;
    }
  }
  __syncthreads();

  // ---- layer 1: feats(64x96) @ W1(96x128) -> h1T in bufB ----
  float acc[4][8];
#pragma unroll
  for (int i = 0; i < 4; ++i)
#pragma unroll
    for (int j = 0; j < 8; ++j) acc[i][j] = 0.f;

#pragma unroll 4
  for (int kk = 0; kk < 96; ++kk) {
    const float4 a = *(const float4*)(bufA + kk * 64 + ((tm ^ (kk & 7)) << 2));
    const float4 b0 = *(const float4*)(W1 + kk * H_ + 8 * tn);
    const float4 b1v = *(const float4*)(W1 + kk * H_ + 8 * tn + 4);
    const float af[4] = {a.x, a.y, a.z, a.w};
    const float bf[8] = {b0.x, b0.y, b0.z, b0.w, b1v.x, b1v.y, b1v.z, b1v.w};
#pragma unroll
    for (int i = 0; i < 4; ++i)
#pragma unroll
      for (int j = 0; j < 8; ++j) acc[i][j] = fmaf(af[i], bf[j], acc[i][j]);
  }
  {
    const float4 ba = *(const float4*)(b1 + 8 * tn);
    const float4 bb = *(const float4*)(b1 + 8 * tn + 4);
    const float bias[8] = {ba.x, ba.y, ba.z, ba.w, bb.x, bb.y, bb.z, bb.w};
#pragma unroll
    for (int jj = 0; jj < 8; ++jj) {
      const int n = 8 * tn + jj;
      float4 v;
      v.x = fmaxf(acc[0][jj] + bias[jj], 0.f);
      v.y = fmaxf(acc[1][jj] + bias[jj], 0.f);
      v.z = fmaxf(acc[2][jj] + bias[jj], 0.f);
      v.w = fmaxf(acc[3][jj] + bias[jj], 0.f);
      *(float4*)(bufB + n * 64 + ((tm ^ jj) << 2)) = v;
    }
  }
  __syncthreads();

  // ---- layer 2: h1(64x128) @ W2(128x128) -> h2 in bufA (row-major, swizzled units) ----
#pragma unroll
  for (int i = 0; i < 4; ++i)
#pragma unroll
    for (int j = 0; j < 8; ++j) acc[i][j] = 0.f;

#pragma unroll 4
  for (int kk = 0; kk < 128; ++kk) {
    const float4 a = *(const float4*)(bufB + kk * 64 + ((tm ^ (kk & 7)) << 2));
    const float4 b0 = *(const float4*)(W2 + kk * H_ + 8 * tn);
    const float4 b1v = *(const float4*)(W2 + kk * H_ + 8 * tn + 4);
    const float af[4] = {a.x, a.y, a.z, a.w};
    const float bf[8] = {b0.x, b0.y, b0.z, b0.w, b1v.x, b1v.y, b1v.z, b1v.w};
#pragma unroll
    for (int i = 0; i < 4; ++i)
#pragma unroll
      for (int j = 0; j < 8; ++j) acc[i][j] = fmaf(af[i], bf[j], acc[i][j]);
  }
  {
    const float4 ba = *(const float4*)(b2 + 8 * tn);
    const float4 bb = *(const float4*)(b2 + 8 * tn + 4);
    const float bias[8] = {ba.x, ba.y, ba.z, ba.w, bb.x, bb.y, bb.z, bb.w};
#pragma unroll
    for (int i = 0; i < 4; ++i) {
      const int m = 4 * tm + i;
      float4 v0, v1;
      v0.x = fmaxf(acc[i][0] + bias[0], 0.f);
      v0.y = fmaxf(acc[i][1] + bias[1], 0.f);
      v0.z = fmaxf(acc[i][2] + bias[2], 0.f);
      v0.w = fmaxf(acc[i][3] + bias[3], 0.f);
      v1.x = fmaxf(acc[i][4] + bias[4], 0.f);
      v1.y = fmaxf(acc[i][5] + bias[5], 0.f);
      v1.z = fmaxf(acc[i][6] + bias[6], 0.f);
      v1.w = fmaxf(acc[i][7] + bias[7], 0.f);
      const int su0 = (2 * tn) ^ (m & 7);
      const int su1 = (2 * tn + 1) ^ (m & 7);
      *(float4*)(bufA + m * H_ + (su0 << 2)) = v0;
      *(float4*)(bufA + m * H_ + (su1 << 2)) = v1;
    }
  }
  __syncthreads();

  // ---- layer 3: out[p][c] = b3[c] + h2[p] . W3T[c] ; activation; store ----
  float acc3 = b3[q];
#pragma unroll
  for (int nc = 0; nc < 32; ++nc) {
    const int su = nc ^ (p & 7);
    const float4 h = *(const float4*)(bufA + p * H_ + (su << 2));
    const float4 w = *(const float4*)(W3T + q * H_ + nc * 4);
    acc3 = fmaf(h.x, w.x, acc3);
    acc3 = fmaf(h.y, w.y, acc3);
    acc3 = fmaf(h.z, w.z, acc3);
    acc3 = fmaf(h.w, w.w, acc3);
  }
  float outv;
  if (q == 0) {
    const float sp = acc3 > 20.f ? acc3 : log1pf(expf(acc3));
    outv = occ ? sp : 0.f;
  } else {
    outv = 1.f / (1.f + expf(-acc3));
  }
  sr[pG * 4 + q] = outv;
}

// ---------------------------------------------------------------------------
// K2: volume rendering, one wave per ray (lane l handles steps 2l, 2l+1)
// ---------------------------------------------------------------------------
__global__ __launch_bounds__(256) void k_render(
    const float* __restrict__ rays_o, const float* __restrict__ rays_d,
    const float4* __restrict__ sr4, float* __restrict__ out) {
  const int lane = threadIdx.x & 63;
  const int ray = blockIdx.x * 4 + (threadIdx.x >> 6);
  const int s = ray >> 11, r = ray & (R_ - 1);
  const float* ob = rays_o + (s * R_ + r) * 3;
  const float* db = rays_d + (s * R_ + r) * 3;
  float nearv, farv;
  near_far(ob[0], ob[1], ob[2], db[0], db[1], db[2], nearv, farv);
  const float delta = (farv - nearv) * (1.0f / K_);

  const int k0 = lane * 2;
  const float4 A = sr4[ray * K_ + k0];
  const float4 B = sr4[ray * K_ + k0 + 1];
  const float tau0 = A.x * delta, tau1 = B.x * delta;
  const float local = tau0 + tau1;
  float scan = local;
#pragma unroll
  for (int off = 1; off < 64; off <<= 1) {
    const float vsh = __shfl_up(scan, off);
    if (lane >= off) scan += vsh;
  }
  const float pre = scan - local;  // sum of taus before step k0
  const float T0 = expf(-pre);
  const float T1 = expf(-(pre + tau0));
  const float a0 = 1.f - expf(-tau0);
  const float a1 = 1.f - expf(-tau1);
  const float w0 = (T0 > 1e-4f) ? a0 * T0 : 0.f;
  const float w1 = (T1 > 1e-4f) ? a1 * T1 : 0.f;
  const float z0 = nearv + (farv - nearv) * ((k0 + 0.5f) * (1.f / K_));
  const float z1 = nearv + (farv - nearv) * ((k0 + 1.5f) * (1.f / K_));

  float sw = w0 + w1;
  float sd = w0 * z0 + w1 * z1;
  float sred = w0 * A.y + w1 * B.y;
  float sgrn = w0 * A.z + w1 * B.z;
  float sblu = w0 * A.w + w1 * B.w;
#pragma unroll
  for (int m = 32; m >= 1; m >>= 1) {
    sw += __shfl_xor(sw, m);
    sd += __shfl_xor(sd, m);
    sred += __shfl_xor(sred, m);
    sgrn += __shfl_xor(sgrn, m);
    sblu += __shfl_xor(sblu, m);
  }
  if (lane == 0) {
    out[ray] = sw;
    out[S_ * R_ + ray] = sd;
    out[2 * S_ * R_ + ray * 3 + 0] = sred;
    out[2 * S_ * R_ + ray * 3 + 1] = sgrn;
    out[2 * S_ * R_ + ray * 3 + 2] = sblu;
  }
}

// ---------------------------------------------------------------------------
extern "C" void kernel_launch(void* const* d_in, const int* in_sizes, int n_in,
                              void* d_out, int out_size, void* d_ws, size_t ws_size,
                              hipStream_t stream) {
  const float* rays_o = (const float*)d_in[0];
  const float* rays_d = (const float*)d_in[1];
  const float* code = (const float*)d_in[2];
  const int* dgrid = (const int*)d_in[3];
  // d_in[4] = grid_size (128, hardcoded)
  const float* W1 = (const float*)d_in[5];
  const float* b1 = (const float*)d_in[6];
  const float* W2 = (const float*)d_in[7];
  const float* b2 = (const float*)d_in[8];
  const float* W3 = (const float*)d_in[9];
  const float* b3 = (const float*)d_in[10];

  float* ws = (float*)d_ws;
  float* codeT = ws + CODET_OFF;
  float* sr = ws + SR_OFF;
  float* W3T = ws + W3T_OFF;

  hipLaunchKernelGGL(k_transpose_code, dim3(12 * 256), dim3(256), 0, stream, code, codeT);
  hipLaunchKernelGGL(k_prep_w3t, dim3(1), dim3(128), 0, stream, W3, W3T);
  hipLaunchKernelGGL(k_fused, dim3((S_ * R_ * K_) / 64), dim3(256), 0, stream,
                     rays_o, rays_d, codeT, dgrid, W1, b1, W2, b2, W3T, b3, sr);
  hipLaunchKernelGGL(k_render, dim3((S_ * R_) / 4), dim3(256), 0, stream,
                     rays_o, rays_d, (const float4*)sr, (float*)d_out);
}

// Round 2
// 812.852 us; speedup vs baseline: 1.6627x; 1.6627x over previous
//
#include <hip/hip_runtime.h>
#include <math.h>

#define S_ 4
#define R_ 2048
#define K_ 128
#define C_ 32
#define RES_ 128
#define G_ 128
#define H_ 128

typedef __bf16 bf16x8 __attribute__((ext_vector_type(8)));
typedef float f32x4 __attribute__((ext_vector_type(4)));

// ws layout (in floats)
#define CODET_OFF 0
#define CODET_SZ  (S_*3*C_*RES_*RES_)   // 6291456
#define SR_OFF    (CODET_OFF + CODET_SZ)
#define SR_SZ     (S_*R_*K_*4)          // 4194304
#define W3T_OFF   (SR_OFF + SR_SZ)      // 512 floats
#define W1F_OFF   (W3T_OFF + 512)       // 128*96 bf16 = 6144 floats
#define W2F_OFF   (W1F_OFF + 6144)      // 128*128 bf16 = 8192 floats

// LDS row pads (element units)
#define FPAD 104   // feats bf16 row (96 + 8)
#define H1PAD 136  // h1 bf16 row (128 + 8)
#define H2PAD 132  // h2 f32 row (128 + 4)

__device__ __forceinline__ unsigned short f2bf(float x) {
  unsigned int u = __float_as_uint(x);
  unsigned int r = u + 0x7fffu + ((u >> 16) & 1u);
  return (unsigned short)(r >> 16);
}

// ---------------------------------------------------------------------------
// K0: transpose code (S,3,C,RES,RES) -> codeT (S,3,RES,RES,C)
// ---------------------------------------------------------------------------
__global__ __launch_bounds__(256) void k_transpose_code(
    const float* __restrict__ src, float* __restrict__ dst) {
  __shared__ float tile[32 * 65];
  const int t = threadIdx.x;
  const int slab = blockIdx.x >> 8;
  const int xy0 = (blockIdx.x & 255) << 6;
  const float* sp = src + slab * (C_ * RES_ * RES_);
  float* dp = dst + slab * (C_ * RES_ * RES_);
  const int i = t & 63, cg = t >> 6;
#pragma unroll
  for (int j = 0; j < 8; ++j) {
    int c = cg * 8 + j;
    tile[c * 65 + i] = sp[c * (RES_ * RES_) + xy0 + i];
  }
  __syncthreads();
  const int c2 = t & 31, xh = t >> 5;
#pragma unroll
  for (int j = 0; j < 8; ++j) {
    int xy = xh * 8 + j;
    dp[(xy0 + xy) * C_ + c2] = tile[c2 * 65 + xy];
  }
}

// ---------------------------------------------------------------------------
// K0b: weight prep. W1(96,128)->W1f bf16 [n][k](128,96); W2->[128][128];
//      W3(128,4)->W3T f32 (4,128)
// ---------------------------------------------------------------------------
__global__ __launch_bounds__(256) void k_prep_w(
    const float* __restrict__ W1, const float* __restrict__ W2,
    const float* __restrict__ W3, unsigned short* __restrict__ W1f,
    unsigned short* __restrict__ W2f, float* __restrict__ W3T) {
  const int t = threadIdx.x;
  for (int i = t; i < 128 * 96; i += 256) {
    const int n = i / 96, k = i - n * 96;
    W1f[i] = f2bf(W1[k * H_ + n]);
  }
  for (int i = t; i < 128 * 128; i += 256) {
    const int n = i >> 7, k = i & 127;
    W2f[i] = f2bf(W2[k * H_ + n]);
  }
  if (t < 128) {
    float4 r = *(const float4*)(W3 + t * 4);
    W3T[0 * H_ + t] = r.x;
    W3T[1 * H_ + t] = r.y;
    W3T[2 * H_ + t] = r.z;
    W3T[3 * H_ + t] = r.w;
  }
}

// ---------------------------------------------------------------------------
__device__ __forceinline__ void near_far(float ox, float oy, float oz,
                                         float dx, float dy, float dz,
                                         float& nearv, float& farv) {
  float ddx = fabsf(dx) < 1e-9f ? 1e-9f : dx;
  float ddy = fabsf(dy) < 1e-9f ? 1e-9f : dy;
  float ddz = fabsf(dz) < 1e-9f ? 1e-9f : dz;
  float ix = 1.f / ddx, iy = 1.f / ddy, iz = 1.f / ddz;
  float t1x = (-1.f - ox) * ix, t2x = (1.f - ox) * ix;
  float t1y = (-1.f - oy) * iy, t2y = (1.f - oy) * iy;
  float t1z = (-1.f - oz) * iz, t2z = (1.f - oz) * iz;
  float mnx = fminf(t1x, t2x), mxx = fmaxf(t1x, t2x);
  float mny = fminf(t1y, t2y), mxy = fmaxf(t1y, t2y);
  float mnz = fminf(t1z, t2z), mxz = fmaxf(t1z, t2z);
  nearv = fmaxf(fmaxf(fmaxf(mnx, mny), mnz), 0.2f);
  farv = fmaxf(fminf(fminf(mxx, mxy), mxz), nearv);
}

// ---------------------------------------------------------------------------
// K1: fused sampling + MLP with bf16 MFMA (16x16x32).
// Block = 256 threads (4 waves), 64 points. Wave w owns M-tile [16w,16w+16).
// LDS: smemA = feats bf16 [64][FPAD] (later aliased by h2 f32 [64][H2PAD])
//      smemB = h1 bf16 [64][H1PAD]
// ---------------------------------------------------------------------------
__global__ __launch_bounds__(256) void k_fused(
    const float* __restrict__ rays_o, const float* __restrict__ rays_d,
    const float* __restrict__ codeT, const int* __restrict__ dgrid,
    const unsigned short* __restrict__ W1f, const float* __restrict__ b1,
    const unsigned short* __restrict__ W2f, const float* __restrict__ b2,
    const float* __restrict__ W3T, const float* __restrict__ b3,
    float* __restrict__ sr) {
  __shared__ __align__(16) float smemA[64 * H2PAD];           // 33792 B
  __shared__ __align__(16) unsigned short smemB[64 * H1PAD];  // 17408 B
  unsigned short* fA = (unsigned short*)smemA;  // feats [64][FPAD]
  float* h2 = smemA;                            // h2 [64][H2PAD]
  unsigned short* h1 = smemB;                   // h1 [64][H1PAD]

  const int t = threadIdx.x;
  const int w = t >> 6, lane = t & 63;
  const int quad = lane >> 4, ln = lane & 15;
  const int p = t >> 2, q = t & 3;  // sampling / layer-3 role
  const int pG = blockIdx.x * 64 + p;
  const int s = pG >> 18;
  const int r = (pG >> 7) & (R_ - 1);
  const int k = pG & (K_ - 1);

  const float* ob = rays_o + (s * R_ + r) * 3;
  const float* db = rays_d + (s * R_ + r) * 3;
  const float ox = ob[0], oy = ob[1], oz = ob[2];
  const float dx = db[0], dy = db[1], dz = db[2];
  float nearv, farv;
  near_far(ox, oy, oz, dx, dy, dz, nearv, farv);

  const float zs = nearv + (farv - nearv) * ((k + 0.5f) * (1.0f / K_));
  const float px = fminf(fmaxf(ox + dx * zs, -1.f), 1.f);
  const float py = fminf(fmaxf(oy + dy * zs, -1.f), 1.f);
  const float pz = fminf(fmaxf(oz + dz * zs, -1.f), 1.f);

  const int i0 = min((int)((px + 1.f) * 64.f), G_ - 1);
  const int i1 = min((int)((py + 1.f) * 64.f), G_ - 1);
  const int i2 = min((int)((pz + 1.f) * 64.f), G_ - 1);
  const int occ = dgrid[((s * G_ + i0) * G_ + i1) * G_ + i2] > 0;

  // ---- triplane sampling: thread covers feats [24q, 24q+24) of point p ----
#pragma unroll
  for (int pl = 0; pl < 3; ++pl) {
    const float u = (pl == 2) ? py : px;
    const float v = (pl == 0) ? py : pz;
    const float fx = (u + 1.f) * 0.5f * 127.f;
    const float fy = (v + 1.f) * 0.5f * 127.f;
    const int xi = min((int)fx, RES_ - 2);
    const int yi = min((int)fy, RES_ - 2);
    const float wx = fx - (float)xi, wy = fy - (float)yi;
    const float w00 = (1.f - wx) * (1.f - wy);
    const float w01 = wx * (1.f - wy);
    const float w10 = (1.f - wx) * wy;
    const float w11 = wx * wy;
    const float* bp = codeT + ((s * 3 + pl) * (RES_ * RES_) + yi * RES_ + xi) * C_;
    const int c0 = max(24 * q - 32 * pl, 0);
    const int c1 = min(24 * q + 24 - 32 * pl, 32);
    for (int c = c0; c < c1; c += 4) {
      const float4 A = *(const float4*)(bp + c);
      const float4 B = *(const float4*)(bp + C_ + c);
      const float4 Cv = *(const float4*)(bp + RES_ * C_ + c);
      const float4 D = *(const float4*)(bp + RES_ * C_ + C_ + c);
      ushort4 pk;
      pk.x = f2bf(w00 * A.x + w01 * B.x + w10 * Cv.x + w11 * D.x);
      pk.y = f2bf(w00 * A.y + w01 * B.y + w10 * Cv.y + w11 * D.y);
      pk.z = f2bf(w00 * A.z + w01 * B.z + w10 * Cv.z + w11 * D.z);
      pk.w = f2bf(w00 * A.w + w01 * B.w + w10 * Cv.w + w11 * D.w);
      const int f = pl * 32 + c;
      *(ushort4*)(fA + p * FPAD + f) = pk;
    }
  }
  __syncthreads();

  // ---- layer 1: feats(64x96) @ W1f^T -> h1 bf16 (MFMA 16x16x32) ----
  {
    f32x4 acc[8];
#pragma unroll
    for (int nt = 0; nt < 8; ++nt) acc[nt] = (f32x4){0.f, 0.f, 0.f, 0.f};
    bf16x8 afr[3];
#pragma unroll
    for (int kt = 0; kt < 3; ++kt)
      afr[kt] = *(const bf16x8*)(fA + (16 * w + ln) * FPAD + kt * 32 + quad * 8);
#pragma unroll
    for (int nt = 0; nt < 8; ++nt) {
      const unsigned short* wp = W1f + (nt * 16 + ln) * 96 + quad * 8;
      const bf16x8 bf0 = *(const bf16x8*)(wp);
      const bf16x8 bf1 = *(const bf16x8*)(wp + 32);
      const bf16x8 bf2 = *(const bf16x8*)(wp + 64);
      acc[nt] = __builtin_amdgcn_mfma_f32_16x16x32_bf16(afr[0], bf0, acc[nt], 0, 0, 0);
      acc[nt] = __builtin_amdgcn_mfma_f32_16x16x32_bf16(afr[1], bf1, acc[nt], 0, 0, 0);
      acc[nt] = __builtin_amdgcn_mfma_f32_16x16x32_bf16(afr[2], bf2, acc[nt], 0, 0, 0);
    }
    // epilogue: bias + relu -> h1 bf16 [m][n]
#pragma unroll
    for (int nt = 0; nt < 8; ++nt) {
      const int n = nt * 16 + ln;
      const float bias = b1[n];
#pragma unroll
      for (int rr = 0; rr < 4; ++rr) {
        const int m = 16 * w + quad * 4 + rr;
        h1[m * H1PAD + n] = f2bf(fmaxf(acc[nt][rr] + bias, 0.f));
      }
    }
  }
  __syncthreads();

  // ---- layer 2: h1(64x128) @ W2f^T -> h2 f32 (MFMA 16x16x32) ----
  {
    f32x4 acc[8];
#pragma unroll
    for (int nt = 0; nt < 8; ++nt) acc[nt] = (f32x4){0.f, 0.f, 0.f, 0.f};
    bf16x8 afr[4];
#pragma unroll
    for (int kt = 0; kt < 4; ++kt)
      afr[kt] = *(const bf16x8*)(h1 + (16 * w + ln) * H1PAD + kt * 32 + quad * 8);
#pragma unroll
    for (int nt = 0; nt < 8; ++nt) {
      const unsigned short* wp = W2f + (nt * 16 + ln) * 128 + quad * 8;
      const bf16x8 bf0 = *(const bf16x8*)(wp);
      const bf16x8 bf1 = *(const bf16x8*)(wp + 32);
      const bf16x8 bf2 = *(const bf16x8*)(wp + 64);
      const bf16x8 bf3 = *(const bf16x8*)(wp + 96);
      acc[nt] = __builtin_amdgcn_mfma_f32_16x16x32_bf16(afr[0], bf0, acc[nt], 0, 0, 0);
      acc[nt] = __builtin_amdgcn_mfma_f32_16x16x32_bf16(afr[1], bf1, acc[nt], 0, 0, 0);
      acc[nt] = __builtin_amdgcn_mfma_f32_16x16x32_bf16(afr[2], bf2, acc[nt], 0, 0, 0);
      acc[nt] = __builtin_amdgcn_mfma_f32_16x16x32_bf16(afr[3], bf3, acc[nt], 0, 0, 0);
    }
    __syncthreads();  // feats reads done everywhere; safe to overwrite smemA as h2
#pragma unroll
    for (int nt = 0; nt < 8; ++nt) {
      const int n = nt * 16 + ln;
      const float bias = b2[n];
#pragma unroll
      for (int rr = 0; rr < 4; ++rr) {
        const int m = 16 * w + quad * 4 + rr;
        h2[m * H2PAD + n] = fmaxf(acc[nt][rr] + bias, 0.f);
      }
    }
  }
  __syncthreads();

  // ---- layer 3: out[p][q] = b3[q] + h2[p] . W3T[q] ----
  float acc3 = b3[q];
#pragma unroll
  for (int nc = 0; nc < 32; ++nc) {
    const float4 h = *(const float4*)(h2 + p * H2PAD + nc * 4);
    const float4 wv = *(const float4*)(W3T + q * H_ + nc * 4);
    acc3 = fmaf(h.x, wv.x, acc3);
    acc3 = fmaf(h.y, wv.y, acc3);
    acc3 = fmaf(h.z, wv.z, acc3);
    acc3 = fmaf(h.w, wv.w, acc3);
  }
  float outv;
  if (q == 0) {
    const float sp = acc3 > 20.f ? acc3 : log1pf(expf(acc3));
    outv = occ ? sp : 0.f;
  } else {
    outv = 1.f / (1.f + expf(-acc3));
  }
  sr[pG * 4 + q] = outv;
}

// ---------------------------------------------------------------------------
// K2: volume rendering, one wave per ray
// ---------------------------------------------------------------------------
__global__ __launch_bounds__(256) void k_render(
    const float* __restrict__ rays_o, const float* __restrict__ rays_d,
    const float4* __restrict__ sr4, float* __restrict__ out) {
  const int lane = threadIdx.x & 63;
  const int ray = blockIdx.x * 4 + (threadIdx.x >> 6);
  const int s = ray >> 11, r = ray & (R_ - 1);
  const float* ob = rays_o + (s * R_ + r) * 3;
  const float* db = rays_d + (s * R_ + r) * 3;
  float nearv, farv;
  near_far(ob[0], ob[1], ob[2], db[0], db[1], db[2], nearv, farv);
  const float delta = (farv - nearv) * (1.0f / K_);

  const int k0 = lane * 2;
  const float4 A = sr4[ray * K_ + k0];
  const float4 B = sr4[ray * K_ + k0 + 1];
  const float tau0 = A.x * delta, tau1 = B.x * delta;
  const float local = tau0 + tau1;
  float scan = local;
#pragma unroll
  for (int off = 1; off < 64; off <<= 1) {
    const float vsh = __shfl_up(scan, off);
    if (lane >= off) scan += vsh;
  }
  const float pre = scan - local;
  const float T0 = expf(-pre);
  const float T1 = expf(-(pre + tau0));
  const float a0 = 1.f - expf(-tau0);
  const float a1 = 1.f - expf(-tau1);
  const float w0 = (T0 > 1e-4f) ? a0 * T0 : 0.f;
  const float w1 = (T1 > 1e-4f) ? a1 * T1 : 0.f;
  const float z0 = nearv + (farv - nearv) * ((k0 + 0.5f) * (1.f / K_));
  const float z1 = nearv + (farv - nearv) * ((k0 + 1.5f) * (1.f / K_));

  float sw = w0 + w1;
  float sd = w0 * z0 + w1 * z1;
  float sred = w0 * A.y + w1 * B.y;
  float sgrn = w0 * A.z + w1 * B.z;
  float sblu = w0 * A.w + w1 * B.w;
#pragma unroll
  for (int m = 32; m >= 1; m >>= 1) {
    sw += __shfl_xor(sw, m);
    sd += __shfl_xor(sd, m);
    sred += __shfl_xor(sred, m);
    sgrn += __shfl_xor(sgrn, m);
    sblu += __shfl_xor(sblu, m);
  }
  if (lane == 0) {
    out[ray] = sw;
    out[S_ * R_ + ray] = sd;
    out[2 * S_ * R_ + ray * 3 + 0] = sred;
    out[2 * S_ * R_ + ray * 3 + 1] = sgrn;
    out[2 * S_ * R_ + ray * 3 + 2] = sblu;
  }
}

// ---------------------------------------------------------------------------
extern "C" void kernel_launch(void* const* d_in, const int* in_sizes, int n_in,
                              void* d_out, int out_size, void* d_ws, size_t ws_size,
                              hipStream_t stream) {
  const float* rays_o = (const float*)d_in[0];
  const float* rays_d = (const float*)d_in[1];
  const float* code = (const float*)d_in[2];
  const int* dgrid = (const int*)d_in[3];
  const float* W1 = (const float*)d_in[5];
  const float* b1 = (const float*)d_in[6];
  const float* W2 = (const float*)d_in[7];
  const float* b2 = (const float*)d_in[8];
  const float* W3 = (const float*)d_in[9];
  const float* b3 = (const float*)d_in[10];

  float* ws = (float*)d_ws;
  float* codeT = ws + CODET_OFF;
  float* sr = ws + SR_OFF;
  float* W3T = ws + W3T_OFF;
  unsigned short* W1f = (unsigned short*)(ws + W1F_OFF);
  unsigned short* W2f = (unsigned short*)(ws + W2F_OFF);

  hipLaunchKernelGGL(k_transpose_code, dim3(12 * 256), dim3(256), 0, stream, code, codeT);
  hipLaunchKernelGGL(k_prep_w, dim3(1), dim3(256), 0, stream, W1, W2, W3, W1f, W2f, W3T);
  hipLaunchKernelGGL(k_fused, dim3((S_ * R_ * K_) / 64), dim3(256), 0, stream,
                     rays_o, rays_d, codeT, dgrid, W1f, b1, W2f, b2, W3T, b3, sr);
  hipLaunchKernelGGL(k_render, dim3((S_ * R_) / 4), dim3(256), 0, stream,
                     rays_o, rays_d, (const float4*)sr, (float*)d_out);
}

// Round 3
// 589.474 us; speedup vs baseline: 2.2927x; 1.3789x over previous
//
#include <hip/hip_runtime.h>
#include <math.h>

#define S_ 4
#define R_ 2048
#define K_ 128
#define C_ 32
#define RES_ 128
#define G_ 128
#define H_ 128

typedef __bf16 bf16x8 __attribute__((ext_vector_type(8)));
typedef float f32x4 __attribute__((ext_vector_type(4)));

// ws layout (in floats)
#define CODET_OFF 0
#define CODET_SZ  (S_*3*C_*RES_*RES_)   // 6291456
#define SR_OFF    (CODET_OFF + CODET_SZ)
#define SR_SZ     (S_*R_*K_*4)          // 4194304
#define W1F_OFF   (SR_OFF + SR_SZ)      // 128*96 bf16 = 6144 floats
#define W2F_OFF   (W1F_OFF + 6144)      // 128*128 bf16 = 8192 floats

// LDS row pads (bf16-element units)
#define FPAD 104   // feats row: 96 + 8  (208B stride -> 2-way banks = free)
#define H1PAD 136  // h1 row: 128 + 8    (272B stride -> 2-way banks = free)

__device__ __forceinline__ unsigned short f2bf(float x) {
  unsigned int u = __float_as_uint(x);
  unsigned int r = u + 0x7fffu + ((u >> 16) & 1u);
  return (unsigned short)(r >> 16);
}

// ---------------------------------------------------------------------------
// K0: transpose code (S,3,C,RES,RES) -> codeT (S,3,RES,RES,C)
// ---------------------------------------------------------------------------
__global__ __launch_bounds__(256) void k_transpose_code(
    const float* __restrict__ src, float* __restrict__ dst) {
  __shared__ float tile[32 * 65];
  const int t = threadIdx.x;
  const int slab = blockIdx.x >> 8;
  const int xy0 = (blockIdx.x & 255) << 6;
  const float* sp = src + slab * (C_ * RES_ * RES_);
  float* dp = dst + slab * (C_ * RES_ * RES_);
  const int i = t & 63, cg = t >> 6;
#pragma unroll
  for (int j = 0; j < 8; ++j) {
    int c = cg * 8 + j;
    tile[c * 65 + i] = sp[c * (RES_ * RES_) + xy0 + i];
  }
  __syncthreads();
  const int c2 = t & 31, xh = t >> 5;
#pragma unroll
  for (int j = 0; j < 8; ++j) {
    int xy = xh * 8 + j;
    dp[(xy0 + xy) * C_ + c2] = tile[c2 * 65 + xy];
  }
}

// ---------------------------------------------------------------------------
// K0b: weight prep. W1(96,128)->W1f bf16 [n][k]; W2(128,128)->W2f bf16 [n][k]
// ---------------------------------------------------------------------------
__global__ __launch_bounds__(256) void k_prep_w(
    const float* __restrict__ W1, const float* __restrict__ W2,
    unsigned short* __restrict__ W1f, unsigned short* __restrict__ W2f) {
  const int t = threadIdx.x;
  for (int i = t; i < 128 * 96; i += 256) {
    const int n = i / 96, k = i - n * 96;
    W1f[i] = f2bf(W1[k * H_ + n]);
  }
  for (int i = t; i < 128 * 128; i += 256) {
    const int n = i >> 7, k = i & 127;
    W2f[i] = f2bf(W2[k * H_ + n]);
  }
}

// ---------------------------------------------------------------------------
__device__ __forceinline__ void near_far(float ox, float oy, float oz,
                                         float dx, float dy, float dz,
                                         float& nearv, float& farv) {
  float ddx = fabsf(dx) < 1e-9f ? 1e-9f : dx;
  float ddy = fabsf(dy) < 1e-9f ? 1e-9f : dy;
  float ddz = fabsf(dz) < 1e-9f ? 1e-9f : dz;
  float ix = 1.f / ddx, iy = 1.f / ddy, iz = 1.f / ddz;
  float t1x = (-1.f - ox) * ix, t2x = (1.f - ox) * ix;
  float t1y = (-1.f - oy) * iy, t2y = (1.f - oy) * iy;
  float t1z = (-1.f - oz) * iz, t2z = (1.f - oz) * iz;
  float mnx = fminf(t1x, t2x), mxx = fmaxf(t1x, t2x);
  float mny = fminf(t1y, t2y), mxy = fmaxf(t1y, t2y);
  float mnz = fminf(t1z, t2z), mxz = fmaxf(t1z, t2z);
  nearv = fmaxf(fmaxf(fmaxf(mnx, mny), mnz), 0.2f);
  farv = fmaxf(fminf(fminf(mxx, mxy), mxz), nearv);
}

// ---------------------------------------------------------------------------
// K1: fused sampling + MLP. 256 threads (4 waves), 64 points = half a ray
// (ray is block-uniform). Wave w owns M-tile [16w,16w+16), full N=128.
// Layer 3 is done in-register from layer-2 accumulators (no h2 buffer).
// Only 2 barriers per block.
// ---------------------------------------------------------------------------
__global__ __launch_bounds__(256, 4) void k_fused(
    const float* __restrict__ rays_o, const float* __restrict__ rays_d,
    const float* __restrict__ codeT, const int* __restrict__ dgrid,
    const unsigned short* __restrict__ W1f, const float* __restrict__ b1,
    const unsigned short* __restrict__ W2f, const float* __restrict__ b2,
    const float* __restrict__ W3, const float* __restrict__ b3,
    float* __restrict__ sr) {
  __shared__ __align__(16) unsigned short fA[64 * FPAD];   // 13312 B
  __shared__ __align__(16) unsigned short h1s[64 * H1PAD]; // 17408 B

  const int t = threadIdx.x;
  const int w = t >> 6, lane = t & 63;
  const int quad = lane >> 4, ln = lane & 15;
  const int p = t >> 2, q = t & 3;     // sampling role: point p, channel-quarter q
  const int pG0 = blockIdx.x * 64;
  const int s = blockIdx.x >> 12;              // pG>>18
  const int r = (blockIdx.x >> 1) & (R_ - 1);  // pG>>7
  const int kbase = (blockIdx.x & 1) * 64;

  // ---- block-uniform ray ----
  const float* ob = rays_o + (s * R_ + r) * 3;
  const float* db = rays_d + (s * R_ + r) * 3;
  const float ox = ob[0], oy = ob[1], oz = ob[2];
  const float dx = db[0], dy = db[1], dz = db[2];
  float nearv, farv;
  near_far(ox, oy, oz, dx, dy, dz, nearv, farv);

  // ---- this thread's sample point ----
  const float zs = nearv + (farv - nearv) * ((kbase + p + 0.5f) * (1.0f / K_));
  const float px = fminf(fmaxf(ox + dx * zs, -1.f), 1.f);
  const float py = fminf(fmaxf(oy + dy * zs, -1.f), 1.f);
  const float pz = fminf(fmaxf(oz + dz * zs, -1.f), 1.f);

  // ---- per-plane bilinear setup (planes: (x,y), (x,z), (y,z)) ----
  int offp[2 * 3];  // flattened manually below
  float w00a, w01a, w10a, w11a, w00b, w01b, w10b, w11b, w00c, w01c, w10c, w11c;
  int off0, off1, off2;
  {
    // plane 0: u=px, v=py
    float fx = (px + 1.f) * 0.5f * 127.f, fy = (py + 1.f) * 0.5f * 127.f;
    int xi = min((int)fx, RES_ - 2), yi = min((int)fy, RES_ - 2);
    float wx = fx - (float)xi, wy = fy - (float)yi;
    w00a = (1.f - wx) * (1.f - wy); w01a = wx * (1.f - wy);
    w10a = (1.f - wx) * wy;         w11a = wx * wy;
    off0 = ((s * 3 + 0) * (RES_ * RES_) + yi * RES_ + xi) * C_;
  }
  {
    // plane 1: u=px, v=pz
    float fx = (px + 1.f) * 0.5f * 127.f, fy = (pz + 1.f) * 0.5f * 127.f;
    int xi = min((int)fx, RES_ - 2), yi = min((int)fy, RES_ - 2);
    float wx = fx - (float)xi, wy = fy - (float)yi;
    w00b = (1.f - wx) * (1.f - wy); w01b = wx * (1.f - wy);
    w10b = (1.f - wx) * wy;         w11b = wx * wy;
    off1 = ((s * 3 + 1) * (RES_ * RES_) + yi * RES_ + xi) * C_;
  }
  {
    // plane 2: u=py, v=pz
    float fx = (py + 1.f) * 0.5f * 127.f, fy = (pz + 1.f) * 0.5f * 127.f;
    int xi = min((int)fx, RES_ - 2), yi = min((int)fy, RES_ - 2);
    float wx = fx - (float)xi, wy = fy - (float)yi;
    w00c = (1.f - wx) * (1.f - wy); w01c = wx * (1.f - wy);
    w10c = (1.f - wx) * wy;         w11c = wx * wy;
    off2 = ((s * 3 + 2) * (RES_ * RES_) + yi * RES_ + xi) * C_;
  }
  (void)offp;

  // ---- gather: thread covers channels [24q, 24q+24), 6 groups of 4, unrolled ----
#pragma unroll
  for (int j = 0; j < 6; ++j) {
    const int f = 24 * q + 4 * j;    // global channel of this group
    const int pl = f >> 5;
    const int c = f & 31;
    const int off = (pl == 0) ? off0 : ((pl == 1) ? off1 : off2);
    const float W00 = (pl == 0) ? w00a : ((pl == 1) ? w00b : w00c);
    const float W01 = (pl == 0) ? w01a : ((pl == 1) ? w01b : w01c);
    const float W10 = (pl == 0) ? w10a : ((pl == 1) ? w10b : w10c);
    const float W11 = (pl == 0) ? w11a : ((pl == 1) ? w11b : w11c);
    const float* bp = codeT + off + c;
    const float4 A = *(const float4*)(bp);
    const float4 B = *(const float4*)(bp + C_);
    const float4 Cv = *(const float4*)(bp + RES_ * C_);
    const float4 D = *(const float4*)(bp + RES_ * C_ + C_);
    ushort4 pk;
    pk.x = f2bf(W00 * A.x + W01 * B.x + W10 * Cv.x + W11 * D.x);
    pk.y = f2bf(W00 * A.y + W01 * B.y + W10 * Cv.y + W11 * D.y);
    pk.z = f2bf(W00 * A.z + W01 * B.z + W10 * Cv.z + W11 * D.z);
    pk.w = f2bf(W00 * A.w + W01 * B.w + W10 * Cv.w + W11 * D.w);
    *(ushort4*)(fA + p * FPAD + f) = pk;
  }
  __syncthreads();

  // ---- layer 1: feats(64x96) @ W1f^T -> h1 bf16 ----
  f32x4 acc[8];
  {
#pragma unroll
    for (int nt = 0; nt < 8; ++nt) acc[nt] = (f32x4){0.f, 0.f, 0.f, 0.f};
    bf16x8 afr[3];
#pragma unroll
    for (int kt = 0; kt < 3; ++kt)
      afr[kt] = *(const bf16x8*)(fA + (16 * w + ln) * FPAD + kt * 32 + quad * 8);
#pragma unroll
    for (int nt = 0; nt < 8; ++nt) {
      const unsigned short* wp = W1f + (nt * 16 + ln) * 96 + quad * 8;
      const bf16x8 bf0 = *(const bf16x8*)(wp);
      const bf16x8 bf1 = *(const bf16x8*)(wp + 32);
      const bf16x8 bf2 = *(const bf16x8*)(wp + 64);
      acc[nt] = __builtin_amdgcn_mfma_f32_16x16x32_bf16(afr[0], bf0, acc[nt], 0, 0, 0);
      acc[nt] = __builtin_amdgcn_mfma_f32_16x16x32_bf16(afr[1], bf1, acc[nt], 0, 0, 0);
      acc[nt] = __builtin_amdgcn_mfma_f32_16x16x32_bf16(afr[2], bf2, acc[nt], 0, 0, 0);
    }
#pragma unroll
    for (int nt = 0; nt < 8; ++nt) {
      const int n = nt * 16 + ln;
      const float bias = b1[n];
#pragma unroll
      for (int rr = 0; rr < 4; ++rr) {
        const int m = 16 * w + quad * 4 + rr;
        h1s[m * H1PAD + n] = f2bf(fmaxf(acc[nt][rr] + bias, 0.f));
      }
    }
  }
  __syncthreads();

  // ---- layer 2: h1(64x128) @ W2f^T -> h2 kept in accumulators ----
  {
#pragma unroll
    for (int nt = 0; nt < 8; ++nt) acc[nt] = (f32x4){0.f, 0.f, 0.f, 0.f};
    bf16x8 afr[4];
#pragma unroll
    for (int kt = 0; kt < 4; ++kt)
      afr[kt] = *(const bf16x8*)(h1s + (16 * w + ln) * H1PAD + kt * 32 + quad * 8);
#pragma unroll
    for (int nt = 0; nt < 8; ++nt) {
      const unsigned short* wp = W2f + (nt * 16 + ln) * 128 + quad * 8;
      const bf16x8 bf0 = *(const bf16x8*)(wp);
      const bf16x8 bf1 = *(const bf16x8*)(wp + 32);
      const bf16x8 bf2 = *(const bf16x8*)(wp + 64);
      const bf16x8 bf3 = *(const bf16x8*)(wp + 96);
      acc[nt] = __builtin_amdgcn_mfma_f32_16x16x32_bf16(afr[0], bf0, acc[nt], 0, 0, 0);
      acc[nt] = __builtin_amdgcn_mfma_f32_16x16x32_bf16(afr[1], bf1, acc[nt], 0, 0, 0);
      acc[nt] = __builtin_amdgcn_mfma_f32_16x16x32_bf16(afr[2], bf2, acc[nt], 0, 0, 0);
      acc[nt] = __builtin_amdgcn_mfma_f32_16x16x32_bf16(afr[3], bf3, acc[nt], 0, 0, 0);
    }
  }

  // ---- layer 3 in-register: part[rr][q] = sum_n relu(h2)*W3[n][q] ----
  float part[4][4];
#pragma unroll
  for (int rr = 0; rr < 4; ++rr)
#pragma unroll
    for (int qq = 0; qq < 4; ++qq) part[rr][qq] = 0.f;
#pragma unroll
  for (int nt = 0; nt < 8; ++nt) {
    const int n = nt * 16 + ln;
    const float b2n = b2[n];
    const float4 w3v = *(const float4*)(W3 + n * 4);
#pragma unroll
    for (int rr = 0; rr < 4; ++rr) {
      const float hv = fmaxf(acc[nt][rr] + b2n, 0.f);
      part[rr][0] = fmaf(hv, w3v.x, part[rr][0]);
      part[rr][1] = fmaf(hv, w3v.y, part[rr][1]);
      part[rr][2] = fmaf(hv, w3v.z, part[rr][2]);
      part[rr][3] = fmaf(hv, w3v.w, part[rr][3]);
    }
  }
  // pair-halving butterfly over the 16 ln-lanes: lane ln ends with slot ln
  // (slot i = rr*4+q, slot bit k <-> ln bit k)
  float v16[16];
#pragma unroll
  for (int rr = 0; rr < 4; ++rr)
#pragma unroll
    for (int qq = 0; qq < 4; ++qq) v16[rr * 4 + qq] = part[rr][qq];
  float v8[8];
#pragma unroll
  for (int j = 0; j < 8; ++j) {
    const float a = v16[2 * j], c = v16[2 * j + 1];
    const float send = (ln & 1) ? a : c;
    const float keep = (ln & 1) ? c : a;
    v8[j] = keep + __shfl_xor(send, 1);
  }
  float v4a[4];
#pragma unroll
  for (int j = 0; j < 4; ++j) {
    const float a = v8[2 * j], c = v8[2 * j + 1];
    const float send = (ln & 2) ? a : c;
    const float keep = (ln & 2) ? c : a;
    v4a[j] = keep + __shfl_xor(send, 2);
  }
  float v2a[2];
#pragma unroll
  for (int j = 0; j < 2; ++j) {
    const float a = v4a[2 * j], c = v4a[2 * j + 1];
    const float send = (ln & 4) ? a : c;
    const float keep = (ln & 4) ? c : a;
    v2a[j] = keep + __shfl_xor(send, 4);
  }
  float v1;
  {
    const float a = v2a[0], c = v2a[1];
    const float send = (ln & 8) ? a : c;
    const float keep = (ln & 8) ? c : a;
    v1 = keep + __shfl_xor(send, 8);
  }

  // ---- activation + occupancy + store: lane -> (m = 16w+quad*4+(ln>>2), q=ln&3)
  const int q_s = ln & 3, rr_s = ln >> 2;
  const int m = 16 * w + quad * 4 + rr_s;
  const float val = v1 + b3[q_s];

  float outv;
  if (q_s == 0) {
    // recompute occupancy for point m (ray is block-uniform)
    const float zm = nearv + (farv - nearv) * ((kbase + m + 0.5f) * (1.0f / K_));
    const float pxm = fminf(fmaxf(ox + dx * zm, -1.f), 1.f);
    const float pym = fminf(fmaxf(oy + dy * zm, -1.f), 1.f);
    const float pzm = fminf(fmaxf(oz + dz * zm, -1.f), 1.f);
    const int i0 = min((int)((pxm + 1.f) * 64.f), G_ - 1);
    const int i1 = min((int)((pym + 1.f) * 64.f), G_ - 1);
    const int i2 = min((int)((pzm + 1.f) * 64.f), G_ - 1);
    const int occ = dgrid[((s * G_ + i0) * G_ + i1) * G_ + i2] > 0;
    const float sp = val > 20.f ? val : log1pf(expf(val));
    outv = occ ? sp : 0.f;
  } else {
    outv = 1.f / (1.f + expf(-val));
  }
  sr[(pG0 + m) * 4 + q_s] = outv;
}

// ---------------------------------------------------------------------------
// K2: volume rendering, one wave per ray
// ---------------------------------------------------------------------------
__global__ __launch_bounds__(256) void k_render(
    const float* __restrict__ rays_o, const float* __restrict__ rays_d,
    const float4* __restrict__ sr4, float* __restrict__ out) {
  const int lane = threadIdx.x & 63;
  const int ray = blockIdx.x * 4 + (threadIdx.x >> 6);
  const int s = ray >> 11, r = ray & (R_ - 1);
  const float* ob = rays_o + (s * R_ + r) * 3;
  const float* db = rays_d + (s * R_ + r) * 3;
  float nearv, farv;
  near_far(ob[0], ob[1], ob[2], db[0], db[1], db[2], nearv, farv);
  const float delta = (farv - nearv) * (1.0f / K_);

  const int k0 = lane * 2;
  const float4 A = sr4[ray * K_ + k0];
  const float4 B = sr4[ray * K_ + k0 + 1];
  const float tau0 = A.x * delta, tau1 = B.x * delta;
  const float local = tau0 + tau1;
  float scan = local;
#pragma unroll
  for (int off = 1; off < 64; off <<= 1) {
    const float vsh = __shfl_up(scan, off);
    if (lane >= off) scan += vsh;
  }
  const float pre = scan - local;
  const float T0 = expf(-pre);
  const float T1 = expf(-(pre + tau0));
  const float a0 = 1.f - expf(-tau0);
  const float a1 = 1.f - expf(-tau1);
  const float w0 = (T0 > 1e-4f) ? a0 * T0 : 0.f;
  const float w1 = (T1 > 1e-4f) ? a1 * T1 : 0.f;
  const float z0 = nearv + (farv - nearv) * ((k0 + 0.5f) * (1.f / K_));
  const float z1 = nearv + (farv - nearv) * ((k0 + 1.5f) * (1.f / K_));

  float sw = w0 + w1;
  float sd = w0 * z0 + w1 * z1;
  float sred = w0 * A.y + w1 * B.y;
  float sgrn = w0 * A.z + w1 * B.z;
  float sblu = w0 * A.w + w1 * B.w;
#pragma unroll
  for (int m = 32; m >= 1; m >>= 1) {
    sw += __shfl_xor(sw, m);
    sd += __shfl_xor(sd, m);
    sred += __shfl_xor(sred, m);
    sgrn += __shfl_xor(sgrn, m);
    sblu += __shfl_xor(sblu, m);
  }
  if (lane == 0) {
    out[ray] = sw;
    out[S_ * R_ + ray] = sd;
    out[2 * S_ * R_ + ray * 3 + 0] = sred;
    out[2 * S_ * R_ + ray * 3 + 1] = sgrn;
    out[2 * S_ * R_ + ray * 3 + 2] = sblu;
  }
}

// ---------------------------------------------------------------------------
extern "C" void kernel_launch(void* const* d_in, const int* in_sizes, int n_in,
                              void* d_out, int out_size, void* d_ws, size_t ws_size,
                              hipStream_t stream) {
  const float* rays_o = (const float*)d_in[0];
  const float* rays_d = (const float*)d_in[1];
  const float* code = (const float*)d_in[2];
  const int* dgrid = (const int*)d_in[3];
  const float* W1 = (const float*)d_in[5];
  const float* b1 = (const float*)d_in[6];
  const float* W2 = (const float*)d_in[7];
  const float* b2 = (const float*)d_in[8];
  const float* W3 = (const float*)d_in[9];
  const float* b3 = (const float*)d_in[10];

  float* ws = (float*)d_ws;
  float* codeT = ws + CODET_OFF;
  float* sr = ws + SR_OFF;
  unsigned short* W1f = (unsigned short*)(ws + W1F_OFF);
  unsigned short* W2f = (unsigned short*)(ws + W2F_OFF);

  hipLaunchKernelGGL(k_transpose_code, dim3(12 * 256), dim3(256), 0, stream, code, codeT);
  hipLaunchKernelGGL(k_prep_w, dim3(1), dim3(256), 0, stream, W1, W2, W1f, W2f);
  hipLaunchKernelGGL(k_fused, dim3((S_ * R_ * K_) / 64), dim3(256), 0, stream,
                     rays_o, rays_d, codeT, dgrid, W1f, b1, W2f, b2, W3, b3, sr);
  hipLaunchKernelGGL(k_render, dim3((S_ * R_) / 4), dim3(256), 0, stream,
                     rays_o, rays_d, (const float4*)sr, (float*)d_out);
}